// Round 5
// baseline (131.516 us; speedup 1.0000x reference)
//
#include <hip/hip_runtime.h>

#define BB 4
#define NN 4
#define TT 4
#define AA 128
#define DD 64
#define HWD 36864              // 192*192
#define NG (BB * TT * AA)      // 2048
#define SL 128                 // slabs per image
#define SPTS (HWD / SL)        // 288 points per slab
#define NBLK (BB * TT * SL)    // 2048 blocks

__device__ __constant__ int c_ti[4] = {0, 0, 0, 1};
__device__ __constant__ int c_tj[4] = {1, 1, 2, 2};
__device__ __constant__ int c_tk[4] = {2, 3, 3, 3};

// ---------------------------------------------------------------------------
// K1: block (bt, slab) = 64 threads (1 wave). Each lane owns TWO queries
// (tid and tid+64) kept in registers; the wave streams its 288-point slab of
// image tj straight from global (uniform address -> one L2 broadcast per
// point, no LDS). Key = s2 - 2*dot (order-equivalent; per-query sq added at
// combine). Writes per-slab partials (plain stores).
// ---------------------------------------------------------------------------
__global__ __launch_bounds__(64) void
scan1_kernel(const float* __restrict__ pts,
             const int* __restrict__ anchor_idx,
             float* __restrict__ pkey1,
             int* __restrict__ pidx1) {
#pragma clang fp contract(off)
    const int slab = blockIdx.x & (SL - 1);
    const int bt = blockIdx.x >> 7;
    const int t = bt & 3;
    const int b = bt >> 2;
    const int tid = threadIdx.x;          // 0..63
    const int g0 = bt * AA + tid;
    const int g1 = g0 + 64;

    const long ibase = (long)(b * NN + c_ti[t]) * HWD;
    const int q0 = anchor_idx[g0];
    const int q1 = anchor_idx[g1];
    const float* qp0 = pts + (ibase + q0) * 3;
    const float* qp1 = pts + (ibase + q1) * 3;
    const float m2x0 = -2.0f * qp0[0], m2y0 = -2.0f * qp0[1], m2z0 = -2.0f * qp0[2];
    const float m2x1 = -2.0f * qp1[0], m2y1 = -2.0f * qp1[1], m2z1 = -2.0f * qp1[2];

    const float* src =
        pts + ((long)(b * NN + c_tj[t]) * HWD + slab * SPTS) * 3;

    float best0 = 3.4e38f, best1 = 3.4e38f;
    int bi0 = 0, bi1 = 0;
#pragma unroll 4
    for (int p = 0; p < SPTS; ++p) {
        const float x = src[p * 3 + 0];
        const float y = src[p * 3 + 1];
        const float z = src[p * 3 + 2];
        const float s2 = x * x + y * y + z * z;
        const float k0 = fmaf(x, m2x0, fmaf(y, m2y0, fmaf(z, m2z0, s2)));
        const float k1 = fmaf(x, m2x1, fmaf(y, m2y1, fmaf(z, m2z1, s2)));
        if (k0 < best0) { best0 = k0; bi0 = p; }   // ascending -> first occ
        if (k1 < best1) { best1 = k1; bi1 = p; }
    }
    pkey1[slab * NG + g0] = best0;
    pidx1[slab * NG + g0] = slab * SPTS + bi0;
    pkey1[slab * NG + g1] = best1;
    pidx1[slab * NG + g1] = slab * SPTS + bi1;
}

// ---------------------------------------------------------------------------
// K2: same grid. Combine1 in-register (key-only slab scan, coalesced; winner
// slab's idx fetched once; first-min-slab => first occurrence). slab==0
// blocks publish min_ij / idx_j. Then scan image tk with query = pts_j[idx_j].
// Block 0 zeroes K3's finish counter.
// ---------------------------------------------------------------------------
__global__ __launch_bounds__(64) void
scan2_kernel(const float* __restrict__ pts,
             const int* __restrict__ anchor_idx,
             const float* __restrict__ pkey1,
             const int* __restrict__ pidx1,
             float* __restrict__ min_ij,
             int* __restrict__ idx_j_out,
             float* __restrict__ pkey2,
             int* __restrict__ pidx2,
             int* __restrict__ ctr) {
#pragma clang fp contract(off)
    const int slab = blockIdx.x & (SL - 1);
    const int bt = blockIdx.x >> 7;
    const int t = bt & 3;
    const int b = bt >> 2;
    const int tid = threadIdx.x;
    const int g0 = bt * AA + tid;
    const int g1 = g0 + 64;

    if (blockIdx.x == 0 && tid == 0) ctr[0] = 0;

    // combine1: key-only scan over slabs, then one idx fetch per query
    float bk0 = 3.4e38f, bk1 = 3.4e38f;
    int s0 = 0, s1 = 0;
#pragma unroll 4
    for (int c = 0; c < SL; ++c) {
        const float k0 = pkey1[c * NG + g0];
        const float k1 = pkey1[c * NG + g1];
        if (k0 < bk0) { bk0 = k0; s0 = c; }   // ascending c -> first occ
        if (k1 < bk1) { bk1 = k1; s1 = c; }
    }
    const int ij0 = pidx1[s0 * NG + g0];
    const int ij1 = pidx1[s1 * NG + g1];

    if (slab == 0) {
        const long ibase = (long)(b * NN + c_ti[t]) * HWD;
        {
            const float* qp = pts + (ibase + anchor_idx[g0]) * 3;
            const float x = qp[0], y = qp[1], z = qp[2];
            min_ij[g0] = sqrtf(fmaxf(bk0 + (x * x + y * y + z * z), 0.0f));
            idx_j_out[g0] = ij0;
        }
        {
            const float* qp = pts + (ibase + anchor_idx[g1]) * 3;
            const float x = qp[0], y = qp[1], z = qp[2];
            min_ij[g1] = sqrtf(fmaxf(bk1 + (x * x + y * y + z * z), 0.0f));
            idx_j_out[g1] = ij1;
        }
    }

    // scan2: queries = chosen points of image tj
    const long jbase = (long)(b * NN + c_tj[t]) * HWD;
    const float* jp0 = pts + (jbase + ij0) * 3;
    const float* jp1 = pts + (jbase + ij1) * 3;
    const float m2x0 = -2.0f * jp0[0], m2y0 = -2.0f * jp0[1], m2z0 = -2.0f * jp0[2];
    const float m2x1 = -2.0f * jp1[0], m2y1 = -2.0f * jp1[1], m2z1 = -2.0f * jp1[2];

    const float* src =
        pts + ((long)(b * NN + c_tk[t]) * HWD + slab * SPTS) * 3;

    float best0 = 3.4e38f, best1 = 3.4e38f;
    int bi0 = 0, bi1 = 0;
#pragma unroll 4
    for (int p = 0; p < SPTS; ++p) {
        const float x = src[p * 3 + 0];
        const float y = src[p * 3 + 1];
        const float z = src[p * 3 + 2];
        const float s2 = x * x + y * y + z * z;
        const float k0 = fmaf(x, m2x0, fmaf(y, m2y0, fmaf(z, m2z0, s2)));
        const float k1 = fmaf(x, m2x1, fmaf(y, m2y1, fmaf(z, m2z1, s2)));
        if (k0 < best0) { best0 = k0; bi0 = p; }
        if (k1 < best1) { best1 = k1; bi1 = p; }
    }
    pkey2[slab * NG + g0] = best0;
    pidx2[slab * NG + g0] = slab * SPTS + bi0;
    pkey2[slab * NG + g1] = best1;
    pidx2[slab * NG + g1] = slab * SPTS + bi1;
}

// ---------------------------------------------------------------------------
// K3: 16 blocks (one per bt), 128 threads (one per anchor).
//   combine2 -> min_jk/idx_k; dki vs LDS-staged anchors; feature SE;
//   block reduce -> loss_bt/batch_ok; finish-counter; last block -> scalar.
// ---------------------------------------------------------------------------
__global__ __launch_bounds__(128) void
pass3_kernel(const float* __restrict__ pts,
             const float* __restrict__ feats,
             const int* __restrict__ anchor_idx,
             const float* __restrict__ min_ij,
             const int* __restrict__ idx_j_in,
             const float* __restrict__ pkey2,
             const int* __restrict__ pidx2,
             float* __restrict__ loss_bt,
             float* __restrict__ batch_ok,
             int* __restrict__ ctr,
             float* __restrict__ out) {
#pragma clang fp contract(off)
    const int bt = blockIdx.x;
    const int t = bt & 3;
    const int b = bt >> 2;
    const int i = c_ti[t];
    const int k = c_tk[t];
    const int tid = threadIdx.x;
    const int g = bt * AA + tid;

    // combine2
    float bkey = 3.4e38f;
    int ik = 0;
    for (int c = 0; c < SL; ++c) {
        const float kk = pkey2[c * NG + g];
        const int ii = pidx2[c * NG + g];
        if (kk < bkey) { bkey = kk; ik = ii; }
    }
    const int qpj = idx_j_in[g];
    const float* jp = pts + ((long)(b * NN + c_tj[t]) * HWD + qpj) * 3;
    const float jx = jp[0], jy = jp[1], jz = jp[2];
    const float min_jk =
        sqrtf(fmaxf(bkey + (jx * jx + jy * jy + jz * jz), 0.0f));

    // dki
    const int ai = anchor_idx[g];
    const float* ap = pts + ((long)(b * NN + i) * HWD + ai) * 3;
    __shared__ float aps[AA][3];
    aps[tid][0] = ap[0];
    aps[tid][1] = ap[1];
    aps[tid][2] = ap[2];
    const float* kp = pts + ((long)(b * NN + k) * HWD + ik) * 3;
    const float kx = kp[0], ky = kp[1], kz = kp[2];
    const float sk = kx * kx + ky * ky + kz * kz;
    __syncthreads();

    float best = 3.4e38f;
    int besti = 0;
    for (int a2 = 0; a2 < AA; ++a2) {
        const float qx = aps[a2][0], qy = aps[a2][1], qz = aps[a2][2];
        const float s2 = qx * qx + qy * qy + qz * qz;
        const float dot = kx * qx + ky * qy + kz * qz;
        const float d2 = (sk + s2) - 2.0f * dot;
        if (d2 < best) { best = d2; besti = a2; }
    }
    const float min_ki = sqrtf(fmaxf(best, 0.0f));

    const int valid =
        (min_ij[g] < 0.3f) && (min_jk < 0.3f) && (min_ki < 0.3f);

    // feat_ret: reference quirk — raw pixel index besti in [0,128)
    const float* fr = feats + ((long)(b * NN + i) * HWD + besti) * DD;
    const float* fa = feats + ((long)(b * NN + i) * HWD + ai) * DD;
    float snr = 0.0f, sna = 0.0f;
    for (int d = 0; d < DD; ++d) { const float x = fr[d]; snr += x * x; }
    for (int d = 0; d < DD; ++d) { const float y = fa[d]; sna += y * y; }
    const float nr = fmaxf(sqrtf(snr), 1e-12f);
    const float na = fmaxf(sqrtf(sna), 1e-12f);
    float se = 0.0f;
    for (int d = 0; d < DD; ++d) {
        const float x = fr[d] / nr - fa[d] / na;
        se += x * x;
    }

    __shared__ float sred[2][AA];
    sred[0][tid] = (float)valid;
    sred[1][tid] = valid ? se : 0.0f;
    __syncthreads();
    for (int s = 64; s > 0; s >>= 1) {
        if (tid < s) {
            sred[0][tid] += sred[0][tid + s];
            sred[1][tid] += sred[1][tid + s];
        }
        __syncthreads();
    }
    if (tid == 0) {
        const float cnt = sred[0][0];
        const float lbt = (cnt > 0.0f)
                              ? sred[1][0] / (fmaxf(cnt, 1.0f) * (float)DD)
                              : 0.0f;
        const float ok = (cnt >= 5.0f) ? 1.0f : 0.0f;
        atomicExch(&loss_bt[bt], lbt);     // device-scope write-through
        atomicExch(&batch_ok[bt], ok);
        __threadfence();
        const int old = atomicAdd(ctr, 1);
        if (old == 15) {
            float s = 0.0f;
            for (int tt = 0; tt < TT; ++tt) {
                float tc = 0.0f, sl = 0.0f;
                for (int bb = 0; bb < BB; ++bb) {
                    const float okv = atomicAdd(&batch_ok[bb * TT + tt], 0.0f);
                    const float lv = atomicAdd(&loss_bt[bb * TT + tt], 0.0f);
                    tc += okv;
                    sl += lv * okv;
                }
                s += (tc > 0.0f) ? sl / fmaxf(tc, 1.0f) : 0.0f;
            }
            out[0] = s / (float)TT;
        }
    }
}

extern "C" void kernel_launch(void* const* d_in, const int* in_sizes, int n_in,
                              void* d_out, int out_size, void* d_ws,
                              size_t ws_size, hipStream_t stream) {
    const float* feats = (const float*)d_in[0];   // (B,N,H,W,D) f32
    const float* pts = (const float*)d_in[1];     // (B,N,H,W,3) f32
    const int* anchor = (const int*)d_in[2];      // (B,T,A) i32
    float* out = (float*)d_out;

    float* ws = (float*)d_ws;
    float* pkey1 = ws;                               // SL*NG f32 (1 MB)
    int* pidx1 = (int*)(ws + SL * NG);
    float* pkey2 = ws + 2 * SL * NG;
    int* pidx2 = (int*)(ws + 3 * SL * NG);
    float* min_ij = ws + 4 * SL * NG;                // NG
    int* idx_j = (int*)(min_ij + NG);                // NG
    float* loss_bt = min_ij + 2 * NG;                // 16
    float* batch_ok = loss_bt + 16;                  // 16
    int* ctr = (int*)(batch_ok + 16);                // 1

    scan1_kernel<<<NBLK, 64, 0, stream>>>(pts, anchor, pkey1, pidx1);
    scan2_kernel<<<NBLK, 64, 0, stream>>>(pts, anchor, pkey1, pidx1, min_ij,
                                          idx_j, pkey2, pidx2, ctr);
    pass3_kernel<<<BB * TT, 128, 0, stream>>>(pts, feats, anchor, min_ij,
                                              idx_j, pkey2, pidx2, loss_bt,
                                              batch_ok, ctr, out);
}